// Round 18
// baseline (201.094 us; speedup 1.0000x reference)
//
#include <hip/hip_runtime.h>
#include <hip/hip_bf16.h>

#define KD 128   // KEY_DIM
#define VD 64    // VALUE_DIM
#define NA 256   // N_ACTIONS
#define NB 32    // B
#define LL 2048  // L

typedef __attribute__((ext_vector_type(8))) short bf16x8;
typedef __attribute__((ext_vector_type(4))) float f32x4;
typedef __attribute__((ext_vector_type(8))) unsigned short u16x8;
typedef __attribute__((ext_vector_type(4))) unsigned short u16x4;

static __device__ __forceinline__ unsigned short f2bf(float x) {
  __hip_bfloat16 h = __float2bfloat16(x);
  unsigned short u;
  __builtin_memcpy(&u, &h, 2);
  return u;
}

static __device__ __forceinline__ void stage16(const void* gsrc, void* ldst) {
  __builtin_amdgcn_global_load_lds(
      (const __attribute__((address_space(1))) void*)gsrc,
      (__attribute__((address_space(3))) void*)ldst, 16, 0, 0);
}

// convert two LDS-read f32x4 pairs to one bf16x8 fragment
static __device__ __forceinline__ bf16x8 frag_cvt(const f32x4 a, const f32x4 b) {
  u16x8 v;
  v[0] = f2bf(a[0]); v[1] = f2bf(a[1]); v[2] = f2bf(a[2]); v[3] = f2bf(a[3]);
  v[4] = f2bf(b[0]); v[5] = f2bf(b[1]); v[6] = f2bf(b[2]); v[7] = f2bf(b[3]);
  bf16x8 r;
  __builtin_memcpy(&r, &v, 16);
  return r;
}

// ---------------------------------------------------------------
// K1: W2[n][a] = sum_k W[n][k][a]   (128 x 256 fp32)
// ---------------------------------------------------------------
__global__ __launch_bounds__(256) void fold_w(const float* __restrict__ W,
                                              float* __restrict__ W2) {
  const int idx = blockIdx.x * 256 + threadIdx.x;   // n*256 + a
  const int n = idx >> 8, a = idx & 255;
  const float* p = W + (long)n * (VD * NA) + a;
  float s = 0.f;
  #pragma unroll
  for (int k = 0; k < VD; ++k) s += p[k * NA];
  W2[idx] = s;
}

// ---------------------------------------------------------------
// K2: Tt[b][d][n] = sum_a W2[n][a] * V[b][a][d]   (bf16 out, transposed)
// ---------------------------------------------------------------
__global__ __launch_bounds__(128) void compute_t(const float* __restrict__ W2,
                                                 const float* __restrict__ V,
                                                 unsigned short* __restrict__ Tt) {
  const int n = threadIdx.x;
  const int d0 = blockIdx.x * 8;
  const int b = blockIdx.y;
  const float* vb = V + (long)b * NA * KD + d0;
  const float* w2p = W2 + n * NA;
  float acc[8] = {0.f, 0.f, 0.f, 0.f, 0.f, 0.f, 0.f, 0.f};
  for (int a = 0; a < NA; a += 4) {
    const float4 w = *(const float4*)(w2p + a);
    const float wq[4] = {w.x, w.y, w.z, w.w};
    #pragma unroll
    for (int q = 0; q < 4; ++q) {
      const float* vr = vb + (long)(a + q) * KD;
      #pragma unroll
      for (int j = 0; j < 8; ++j) acc[j] += wq[q] * vr[j];
    }
  }
  #pragma unroll
  for (int j = 0; j < 8; ++j)
    Tt[((long)b * KD + d0 + j) * KD + n] = f2bf(acc[j]);
}

// ---------------------------------------------------------------
// K3: FUSED q GEMM reading fp32 key directly (cvt_key + keyB gone).
// Block (b, nt of 8), 256 blocks (1/CU), 512 threads (8 waves,
// 2M x 4N -> wave tile 32x64). BM=64, BN=256, 32 gens.
// A tiles staged RAW FP32 via global_load_lds (dbuf 2x32 KB);
// fp32->bf16 conversion happens on the LDS->reg read in the MFMA
// loop. fp32 swizzle: row = byte>>9 (512-B rows), x = (row&7)<<4.
// Fragment = 32 B = two 16-B halves; lo at fb = linear^x, hi at
// fb ^ 16 (NOT fb+16 — round-17 bug: for odd rows bit4 of fb is
// set and +16 carries into bit5, reading the wrong slot).
// Schedule per gen (validated): stage A(t+1) [4 loads] -> compute
// -> 8 stores -> vmcnt(8) -> s_barrier.
// ---------------------------------------------------------------
__global__ __launch_bounds__(512, 2) void gemm_q(const float* __restrict__ key,
                                                 const unsigned short* __restrict__ Tt,
                                                 float* __restrict__ C) {
  __shared__ unsigned short ldsB[32768];   // 64 KB: Tt high (prologue) -> B panel
  __shared__ float ldsA0[8192];            // 32 KB: fp32 A ping / chunk-half lo
  __shared__ float ldsA1[8192];            // 32 KB: fp32 A pong / chunk-half hi

  // 256 blocks: xcd = bid % 8 owns 32 logical = 4 whole batches
  const int lg = (blockIdx.x & 7) * 32 + (blockIdx.x >> 3);
  const int nt = lg & 7;
  const int b = lg >> 3;

  const int tid = threadIdx.x;
  const int lane = tid & 63, w = tid >> 6;     // 8 waves
  const int l15 = lane & 15, lhi = lane >> 4;
  const int wrM = w >> 2;                      // 0..1 : 32-row half (main loop)
  const int wcN = w & 3;                       // 0..3 : 64-col block (main loop)

  const float* gK = key + (long)b * LL * KD;                    // key[b] fp32
  const unsigned short* gT = Tt + (long)b * KD * KD;            // Tt[b]
  const float* gChunk = gK + (long)nt * 256 * KD;               // B-source rows

  // ---- prologue 1: Tt (32 KB) -> ldsB high ----
  #pragma unroll
  for (int i = 0; i < 4; ++i) {
    const int addr = i * 8192 + tid * 16;
    const int row = addr >> 8;                 // bf16 256-B rows
    const int src = addr ^ ((row & 7) << 4);
    stage16((const char*)gT + src, (char*)ldsB + 32768 + addr);
  }

  // ---- prologue 2: panel = chunk (256x128 fp32) @ Tt^T, 2 halves ----
  f32x4 pacc[2][8];                            // [half][df]
  #pragma unroll
  for (int i = 0; i < 2; ++i)
    #pragma unroll
    for (int j = 0; j < 8; ++j) pacc[i][j] = f32x4{0.f, 0.f, 0.f, 0.f};

  #pragma unroll 1
  for (int h = 0; h < 2; ++h) {
    // stage 128 fp32 rows (64 KB) -> A0|A1
    const char* gsrc = (const char*)(gChunk + (long)h * 128 * KD);
    #pragma unroll
    for (int i = 0; i < 8; ++i) {
      const int addr = i * 8192 + tid * 16;    // 0..64 KB
      const int row = addr >> 9;               // fp32 512-B rows
      const int src = addr ^ ((row & 7) << 4);
      char* dst = (addr < 32768) ? ((char*)ldsA0 + addr) : ((char*)ldsA1 + addr - 32768);
      stage16(gsrc + src, dst);
    }
    asm volatile("s_waitcnt vmcnt(0)" ::: "memory");
    __builtin_amdgcn_s_barrier();
    __builtin_amdgcn_sched_barrier(0);

    // wave w owns half-rows [w*16, +16): 1 rf x 8 df
    #pragma unroll
    for (int ks = 0; ks < 4; ++ks) {
      const int kb = (ks * 32 + lhi * 8) * 2;  // bf16 byte offset (Tt reads)
      const int row = w * 16 + l15;            // 0..127 within half
      const int fb = (row * 512 + (ks * 32 + lhi * 8) * 4) ^ ((row & 7) << 4);
      const int fbh = fb ^ 16;                 // hi half (bit4 permuted slot)
      f32x4 lo, hi;
      if (fb < 32768) {
        lo = *(const f32x4*)((const char*)ldsA0 + fb);
        hi = *(const f32x4*)((const char*)ldsA0 + fbh);
      } else {
        lo = *(const f32x4*)((const char*)ldsA1 + fb - 32768);
        hi = *(const f32x4*)((const char*)ldsA1 + fbh - 32768);
      }
      const bf16x8 av = frag_cvt(lo, hi);
      bf16x8 bv[8];
      #pragma unroll
      for (int df = 0; df < 8; ++df) {
        const int trow = df * 16 + l15;        // Tt row = d
        const int byte = (trow * 256 + kb) ^ ((trow & 7) << 4);
        bv[df] = *(const bf16x8*)((const char*)ldsB + 32768 + byte);
      }
      #pragma unroll
      for (int df = 0; df < 8; ++df)
        pacc[h][df] = __builtin_amdgcn_mfma_f32_16x16x32_bf16(bv[df], av,
                                                              pacc[h][df], 0, 0, 0);
    }
    asm volatile("s_waitcnt lgkmcnt(0)" ::: "memory");
    __builtin_amdgcn_sched_barrier(0);
    __builtin_amdgcn_s_barrier();              // half fully consumed before restage
    __builtin_amdgcn_sched_barrier(0);
  }

  // ---- prologue 3: issue A(0) fp32 stage FIRST, then ds_write panel ----
  #pragma unroll
  for (int i = 0; i < 4; ++i) {
    const int addr = i * 8192 + tid * 16;      // 32 KB (64 fp32 rows)
    const int row = addr >> 9;
    const int src = addr ^ ((row & 7) << 4);
    stage16((const char*)gK + src, (char*)ldsA0 + addr);
  }
  __builtin_amdgcn_sched_barrier(0);
  // panel frag: lane&15 = chunk-row (within 16), lhi*4+reg = d col.
  #pragma unroll
  for (int h = 0; h < 2; ++h)
    #pragma unroll
    for (int df = 0; df < 8; ++df) {
      const int row = h * 128 + w * 16 + l15;  // 0..255
      const int d = df * 16 + lhi * 4;
      u16x4 v;
      #pragma unroll
      for (int i = 0; i < 4; ++i) v[i] = f2bf(pacc[h][df][i]);
      const int byte = (row * 256 + d * 2) ^ ((row & 7) << 4);
      *(u16x4*)((char*)ldsB + byte) = v;
    }
  asm volatile("s_waitcnt vmcnt(0) lgkmcnt(0)" ::: "memory");
  __builtin_amdgcn_sched_barrier(0);
  __builtin_amdgcn_s_barrier();
  __builtin_amdgcn_sched_barrier(0);

  const int col0 = nt * 256 + wcN * 64;

  // ---- main loop: 32 gens of 64x256 ----
  auto gen = [&](int mt, const float* abuf, float* nbuf) {
    // issue next-gen A(mt+1) fp32 stage FIRST (oldest in VM queue)
    if (mt < 31) {
      const char* gA = (const char*)(gK + (long)(mt + 1) * 64 * KD);
      #pragma unroll
      for (int i = 0; i < 4; ++i) {
        const int addr = i * 8192 + tid * 16;
        const int row = addr >> 9;
        const int src = addr ^ ((row & 7) << 4);
        stage16(gA + src, (char*)nbuf + addr);
      }
    }
    __builtin_amdgcn_sched_barrier(0);

    // compute 64x256 from fp32 abuf (cvt on read) + ldsB
    f32x4 acc[2][4];
    #pragma unroll
    for (int i = 0; i < 2; ++i)
      #pragma unroll
      for (int j = 0; j < 4; ++j) acc[i][j] = f32x4{0.f, 0.f, 0.f, 0.f};

    #pragma unroll
    for (int ks = 0; ks < 4; ++ks) {
      const int kb = (ks * 32 + lhi * 8) * 2;
      bf16x8 av[2], bv[4];
      #pragma unroll
      for (int mf = 0; mf < 2; ++mf) {
        const int row = wrM * 32 + mf * 16 + l15;      // 0..63
        const int fb = (row * 512 + (ks * 32 + lhi * 8) * 4) ^ ((row & 7) << 4);
        const f32x4 lo = *(const f32x4*)((const char*)abuf + fb);
        const f32x4 hi = *(const f32x4*)((const char*)abuf + (fb ^ 16));
        av[mf] = frag_cvt(lo, hi);
      }
      #pragma unroll
      for (int nf = 0; nf < 4; ++nf) {
        const int row = wcN * 64 + nf * 16 + l15;      // 0..255
        const int byte = (row * 256 + kb) ^ ((row & 7) << 4);
        bv[nf] = *(const bf16x8*)((const char*)ldsB + byte);
      }
      // swapped operands: lane&15 = out row, (lane>>4)*4+reg = out col
      #pragma unroll
      for (int mf = 0; mf < 2; ++mf)
        #pragma unroll
        for (int nf = 0; nf < 4; ++nf)
          acc[mf][nf] = __builtin_amdgcn_mfma_f32_16x16x32_bf16(bv[nf], av[mf],
                                                                acc[mf][nf], 0, 0, 0);
    }

    // 8 cached dwordx4 stores (fire and forget)
    const long row0 = (long)b * LL + mt * 64 + wrM * 32;
    #pragma unroll
    for (int mf = 0; mf < 2; ++mf)
      #pragma unroll
      for (int nf = 0; nf < 4; ++nf) {
        const long r = row0 + mf * 16 + l15;
        const int c = col0 + nf * 16 + lhi * 4;
        *(f32x4*)(C + r * LL + c) = acc[mf][nf];
      }

    // end-of-gen: drain S(mt-1)+L(mt+1), keep S(mt) in flight
    if (mt < 31) {
      asm volatile("s_waitcnt vmcnt(8)" ::: "memory");
      __builtin_amdgcn_sched_barrier(0);
      __builtin_amdgcn_s_barrier();
      __builtin_amdgcn_sched_barrier(0);
    }
  };

  #pragma unroll 1
  for (int mt2 = 0; mt2 < 16; ++mt2) {
    gen(2 * mt2, ldsA0, ldsA1);
    gen(2 * mt2 + 1, ldsA1, ldsA0);
  }
}

// ---------------------------------------------------------------
// launch
// ---------------------------------------------------------------
extern "C" void kernel_launch(void* const* d_in, const int* in_sizes, int n_in,
                              void* d_out, int out_size, void* d_ws, size_t ws_size,
                              hipStream_t stream) {
  const float* key = (const float*)d_in[0];  // (32, 2048, 128)
  const float* val = (const float*)d_in[1];  // (32, 256, 128)
  const float* wts = (const float*)d_in[2];  // (128, 64, 256)
  float* out = (float*)d_out;                // (32, 2048, 2048) fp32

  // workspace layout
  char* ws = (char*)d_ws;
  float* W2 = (float*)ws;                               // 128 KiB
  unsigned short* Tt = (unsigned short*)(ws + 131072);  // 1 MiB

  fold_w<<<128, 256, 0, stream>>>(wts, W2);
  compute_t<<<dim3(16, NB), 128, 0, stream>>>(W2, val, Tt);
  gemm_q<<<8 * NB, 512, 0, stream>>>(key, Tt, out);
}

// Round 19
// 153.785 us; speedup vs baseline: 1.3076x; 1.3076x over previous
//
#include <hip/hip_runtime.h>
#include <hip/hip_bf16.h>

#define KD 128   // KEY_DIM
#define VD 64    // VALUE_DIM
#define NA 256   // N_ACTIONS
#define NB 32    // B
#define LL 2048  // L

typedef __attribute__((ext_vector_type(8))) short bf16x8;
typedef __attribute__((ext_vector_type(4))) float f32x4;
typedef __attribute__((ext_vector_type(8))) unsigned short u16x8;
typedef __attribute__((ext_vector_type(4))) unsigned short u16x4;

static __device__ __forceinline__ unsigned short f2bf(float x) {
  __hip_bfloat16 h = __float2bfloat16(x);
  unsigned short u;
  __builtin_memcpy(&u, &h, 2);
  return u;
}

static __device__ __forceinline__ void stage16(const void* gsrc, void* ldst) {
  __builtin_amdgcn_global_load_lds(
      (const __attribute__((address_space(1))) void*)gsrc,
      (__attribute__((address_space(3))) void*)ldst, 16, 0, 0);
}

// ---------------------------------------------------------------
// K1: W2[n][a] = sum_k W[n][k][a]   (128 x 256 fp32)
// ---------------------------------------------------------------
__global__ __launch_bounds__(256) void fold_w(const float* __restrict__ W,
                                              float* __restrict__ W2) {
  const int idx = blockIdx.x * 256 + threadIdx.x;   // n*256 + a
  const int n = idx >> 8, a = idx & 255;
  const float* p = W + (long)n * (VD * NA) + a;
  float s = 0.f;
  #pragma unroll
  for (int k = 0; k < VD; ++k) s += p[k * NA];
  W2[idx] = s;
}

// ---------------------------------------------------------------
// K2: Tt[b][d][n] = sum_a W2[n][a] * V[b][a][d]   (bf16 out, transposed)
// ---------------------------------------------------------------
__global__ __launch_bounds__(128) void compute_t(const float* __restrict__ W2,
                                                 const float* __restrict__ V,
                                                 unsigned short* __restrict__ Tt) {
  const int n = threadIdx.x;
  const int d0 = blockIdx.x * 8;
  const int b = blockIdx.y;
  const float* vb = V + (long)b * NA * KD + d0;
  const float* w2p = W2 + n * NA;
  float acc[8] = {0.f, 0.f, 0.f, 0.f, 0.f, 0.f, 0.f, 0.f};
  for (int a = 0; a < NA; a += 4) {
    const float4 w = *(const float4*)(w2p + a);
    const float wq[4] = {w.x, w.y, w.z, w.w};
    #pragma unroll
    for (int q = 0; q < 4; ++q) {
      const float* vr = vb + (long)(a + q) * KD;
      #pragma unroll
      for (int j = 0; j < 8; ++j) acc[j] += wq[q] * vr[j];
    }
  }
  #pragma unroll
  for (int j = 0; j < 8; ++j)
    Tt[((long)b * KD + d0 + j) * KD + n] = f2bf(acc[j]);
}

// ---------------------------------------------------------------
// K3: key fp32 -> bf16, 8 elements/thread
// ---------------------------------------------------------------
__global__ __launch_bounds__(256) void cvt_key(const float* __restrict__ in,
                                               unsigned short* __restrict__ out) {
  const long i = ((long)blockIdx.x * 256 + threadIdx.x) * 8;
  const float4 f0 = *(const float4*)(in + i);
  const float4 f1 = *(const float4*)(in + i + 4);
  u16x8 r;
  r[0] = f2bf(f0.x); r[1] = f2bf(f0.y); r[2] = f2bf(f0.z); r[3] = f2bf(f0.w);
  r[4] = f2bf(f1.x); r[5] = f2bf(f1.y); r[6] = f2bf(f1.z); r[7] = f2bf(f1.w);
  *(u16x8*)(out + i) = r;
}

// ---------------------------------------------------------------
// K4: FUSED q GEMM. Block (b, nt), 256 blocks (1/CU), 512 threads.
// Prologue: stage Tt[b] (32 KB -> low ldsB) + keyB chunk rows
//   [nt*256,+256) (64 KB -> A0|A1); compute the block's own B-panel
//   memB-rows = chunk @ Tt^T (64 MFMA/wave) in registers; convert to
//   bf16; swizzled ds_write into ldsB [256 rows][128 d]. memB never
//   touches HBM. Then the ROUND-10 mt-loop: B-resident, A 2-buffer
//   dbuf with stage A(mt+1) per gen, counted vmcnt(16), raw
//   s_barrier, cached dwordx4 stores.
// LDS: ldsB 64 KB + A0/A1 2x32 KB = 128 KB.
// Best validated: 153.7 us. Probes around it (depth-2 prefetch,
// 2-block TLP, half sync events, nt stores, fp32-direct fusion)
// all neutral-or-worse -> practical roofline for this decomposition.
// ---------------------------------------------------------------
__global__ __launch_bounds__(512, 2) void gemm_q(const unsigned short* __restrict__ A,
                                                 const unsigned short* __restrict__ Tt,
                                                 float* __restrict__ C) {
  __shared__ unsigned short ldsB[32768];   // B panel 64 KB (resident after prologue)
  __shared__ unsigned short ldsA0[16384];  // A tile 32 KB (ping)
  __shared__ unsigned short ldsA1[16384];  // A tile 32 KB (pong)

  // 256 blocks: xcd = bid % 8 owns 32 logical = 4 whole batches
  const int lg = (blockIdx.x & 7) * 32 + (blockIdx.x >> 3);
  const int nt = lg & 7;
  const int b = lg >> 3;

  const int tid = threadIdx.x;
  const int lane = tid & 63, w = tid >> 6;     // 8 waves
  const int l15 = lane & 15, lhi = lane >> 4;
  const int wrM = w >> 2;                      // 0..1 : 64-row half (main loop)
  const int wcN = w & 3;                       // 0..3 : 64-col block (main loop)

  const unsigned short* gAb = A + (long)b * LL * KD;                 // keyB[b]
  const unsigned short* gT = Tt + (long)b * KD * KD;                 // Tt[b]
  const unsigned short* gChunk = gAb + (long)nt * 256 * KD;          // B-source rows

  // ---- prologue 1: stage Tt (32 KB -> ldsB low) + chunk (64 KB -> A0|A1) ----
  #pragma unroll
  for (int i = 0; i < 4; ++i) {
    const int addr = i * 8192 + tid * 16;
    const int row = addr >> 8;
    const int src = addr ^ ((row & 7) << 4);
    stage16((const char*)gT + src, (char*)ldsB + addr);
  }
  #pragma unroll
  for (int i = 0; i < 8; ++i) {
    const int addr = i * 8192 + tid * 16;      // 0..64 KB over chunk
    const int row = addr >> 8;
    const int src = addr ^ ((row & 7) << 4);
    char* dst = (addr < 32768) ? ((char*)ldsA0 + addr) : ((char*)ldsA1 + addr - 32768);
    stage16((const char*)gChunk + src, dst);
  }
  asm volatile("s_waitcnt vmcnt(0)" ::: "memory");
  __builtin_amdgcn_s_barrier();
  __builtin_amdgcn_sched_barrier(0);

  // ---- prologue 2: B-panel = chunk (256x128) @ Tt^T (128x128) in regs ----
  // wave w owns chunk rows [w*32, w*32+32): 2 row-frags x 8 d-frags.
  f32x4 pacc[2][8];
  #pragma unroll
  for (int i = 0; i < 2; ++i)
    #pragma unroll
    for (int j = 0; j < 8; ++j) pacc[i][j] = f32x4{0.f, 0.f, 0.f, 0.f};

  #pragma unroll
  for (int ks = 0; ks < 4; ++ks) {
    const int kb = (ks * 32 + lhi * 8) * 2;
    bf16x8 av[2], bv[8];
    #pragma unroll
    for (int rf = 0; rf < 2; ++rf) {
      const int row = w * 32 + rf * 16 + l15;          // 0..255 in chunk
      const int byte = (row * 256 + kb) ^ ((row & 7) << 4);
      av[rf] = (row < 128)
          ? *(const bf16x8*)((const char*)ldsA0 + byte)
          : *(const bf16x8*)((const char*)ldsA1 + (byte - 32768));
    }
    #pragma unroll
    for (int df = 0; df < 8; ++df) {
      const int row = df * 16 + l15;                   // Tt row = d
      const int byte = (row * 256 + kb) ^ ((row & 7) << 4);
      bv[df] = *(const bf16x8*)((const char*)ldsB + byte);
    }
    #pragma unroll
    for (int rf = 0; rf < 2; ++rf)
      #pragma unroll
      for (int df = 0; df < 8; ++df)
        pacc[rf][df] = __builtin_amdgcn_mfma_f32_16x16x32_bf16(bv[df], av[rf],
                                                               pacc[rf][df], 0, 0, 0);
  }
  // all waves done reading ldsB(Tt)/A0/A1 once past this barrier
  asm volatile("s_waitcnt lgkmcnt(0)" ::: "memory");
  __builtin_amdgcn_sched_barrier(0);
  __builtin_amdgcn_s_barrier();
  __builtin_amdgcn_sched_barrier(0);

  // ---- prologue 3: issue A(0) stage FIRST, then ds_write B-panel ----
  #pragma unroll
  for (int i = 0; i < 4; ++i) {
    const int addr = i * 8192 + tid * 16;
    const int row = addr >> 8;
    const int src = addr ^ ((row & 7) << 4);
    stage16((const char*)gAb + src, (char*)ldsA0 + addr);
  }
  __builtin_amdgcn_sched_barrier(0);
  // B-panel frag: lane&15 = chunk-row (within 16), lhi*4+reg = d col.
  #pragma unroll
  for (int rf = 0; rf < 2; ++rf)
    #pragma unroll
    for (int df = 0; df < 8; ++df) {
      const int row = w * 32 + rf * 16 + l15;          // 0..255
      const int d = df * 16 + lhi * 4;
      u16x4 v;
      #pragma unroll
      for (int i = 0; i < 4; ++i) v[i] = f2bf(pacc[rf][df][i]);
      const int byte = (row * 256 + d * 2) ^ ((row & 7) << 4);
      *(u16x4*)((char*)ldsB + byte) = v;
    }
  asm volatile("s_waitcnt vmcnt(0) lgkmcnt(0)" ::: "memory");
  __builtin_amdgcn_sched_barrier(0);
  __builtin_amdgcn_s_barrier();
  __builtin_amdgcn_sched_barrier(0);

  const int col0 = nt * 256 + wcN * 64;

  // ---- main loop: ROUND-10 schedule (validated) ----
  auto gen = [&](int mt, const unsigned short* abuf, unsigned short* nbuf) {
    // issue next-gen A(mt+1) stage FIRST (oldest in VM queue)
    if (mt < 15) {
      const char* gA = (const char*)(gAb + (long)(mt + 1) * 128 * KD);
      #pragma unroll
      for (int i = 0; i < 4; ++i) {
        const int addr = i * 8192 + tid * 16;
        const int row = addr >> 8;
        const int src = addr ^ ((row & 7) << 4);
        stage16(gA + src, (char*)nbuf + addr);
      }
    }
    __builtin_amdgcn_sched_barrier(0);

    // compute 128x256 from abuf + ldsB
    f32x4 acc[4][4];
    #pragma unroll
    for (int i = 0; i < 4; ++i)
      #pragma unroll
      for (int j = 0; j < 4; ++j) acc[i][j] = f32x4{0.f, 0.f, 0.f, 0.f};

    #pragma unroll
    for (int ks = 0; ks < 4; ++ks) {
      const int kb = (ks * 32 + lhi * 8) * 2;
      bf16x8 av[4], bv[4];
      #pragma unroll
      for (int mf = 0; mf < 4; ++mf) {
        const int row = wrM * 64 + mf * 16 + l15;
        const int byte = (row * 256 + kb) ^ ((row & 7) << 4);
        av[mf] = *(const bf16x8*)((const char*)abuf + byte);
      }
      #pragma unroll
      for (int nf = 0; nf < 4; ++nf) {
        const int row = wcN * 64 + nf * 16 + l15;
        const int byte = (row * 256 + kb) ^ ((row & 7) << 4);
        bv[nf] = *(const bf16x8*)((const char*)ldsB + byte);
      }
      // swapped operands: lane&15 = out row, (lane>>4)*4+reg = out col
      #pragma unroll
      for (int mf = 0; mf < 4; ++mf)
        #pragma unroll
        for (int nf = 0; nf < 4; ++nf)
          acc[mf][nf] = __builtin_amdgcn_mfma_f32_16x16x32_bf16(bv[nf], av[mf],
                                                                acc[mf][nf], 0, 0, 0);
    }

    // 16 cached dwordx4 stores (fire and forget)
    const long row0 = (long)b * LL + mt * 128 + wrM * 64;
    #pragma unroll
    for (int mf = 0; mf < 4; ++mf)
      #pragma unroll
      for (int nf = 0; nf < 4; ++nf) {
        const long r = row0 + mf * 16 + l15;
        const int c = col0 + nf * 16 + lhi * 4;
        *(f32x4*)(C + r * LL + c) = acc[mf][nf];
      }

    // end-of-gen: drain loads(mt+1)+stores(mt-1), keep stores(mt) in flight
    if (mt < 15) {
      asm volatile("s_waitcnt vmcnt(16)" ::: "memory");
      __builtin_amdgcn_sched_barrier(0);
      __builtin_amdgcn_s_barrier();
      __builtin_amdgcn_sched_barrier(0);
    }
  };

  #pragma unroll 1
  for (int mt2 = 0; mt2 < 8; ++mt2) {
    gen(2 * mt2, ldsA0, ldsA1);
    gen(2 * mt2 + 1, ldsA1, ldsA0);
  }
}

// ---------------------------------------------------------------
// launch
// ---------------------------------------------------------------
extern "C" void kernel_launch(void* const* d_in, const int* in_sizes, int n_in,
                              void* d_out, int out_size, void* d_ws, size_t ws_size,
                              hipStream_t stream) {
  const float* key = (const float*)d_in[0];  // (32, 2048, 128)
  const float* val = (const float*)d_in[1];  // (32, 256, 128)
  const float* wts = (const float*)d_in[2];  // (128, 64, 256)
  float* out = (float*)d_out;                // (32, 2048, 2048) fp32

  // workspace layout
  char* ws = (char*)d_ws;
  float* W2 = (float*)ws;                                        // 128 KiB
  unsigned short* Tt = (unsigned short*)(ws + 131072);           // 1 MiB
  unsigned short* keyB = (unsigned short*)(ws + 131072 + 1048576);  // 16 MiB

  fold_w<<<128, 256, 0, stream>>>(wts, W2);
  cvt_key<<<4096, 256, 0, stream>>>(key, keyB);
  compute_t<<<dim3(16, NB), 128, 0, stream>>>(W2, val, Tt);
  gemm_q<<<8 * NB, 512, 0, stream>>>(keyB, Tt, out);
}